// Round 12
// baseline (289.079 us; speedup 1.0000x reference)
//
#include <hip/hip_runtime.h>
#include <math.h>

#define HH   4096
#define NKV  8
#define GRP  4
#define HD   128
#define FFN  11008
#define NB   16
#define SC   4096
#define SCALE 0.08838834764831845f   // 1/sqrt(128)
#define SCH  512                      // attention chunk
#define QKS  8                        // QKV k-split (q partial chunks)

typedef float f4v __attribute__((ext_vector_type(4)));
typedef float f32x4 __attribute__((ext_vector_type(4)));
typedef short bf16x8 __attribute__((ext_vector_type(8)));
typedef unsigned short u16x4 __attribute__((ext_vector_type(4)));
typedef unsigned short u16x8 __attribute__((ext_vector_type(8)));
typedef unsigned int u32x4v __attribute__((ext_vector_type(4)));

__device__ __forceinline__ f4v ntload4(const float* p) {
  return __builtin_nontemporal_load((const f4v*)p);
}
__device__ __forceinline__ float dot4(f4v a, f4v b) {
  return a[0] * b[0] + a[1] * b[1] + a[2] * b[2] + a[3] * b[3];
}
__device__ __forceinline__ unsigned short f2bf(float f) {
  unsigned int u = __builtin_bit_cast(unsigned int, f);
  u += 0x7fffu + ((u >> 16) & 1u);
  return (unsigned short)(u >> 16);
}
__device__ __forceinline__ float silu_f(float g) { return g / (1.f + __expf(-g)); }
// packed fp32->bf16 (RNE) — ATTENTION KERNELS ONLY (GEMV with this asm NaN'd in R8/R9)
__device__ __forceinline__ unsigned int cvtpk(float lo, float hi) {
  unsigned int r;
  asm("v_cvt_pk_bf16_f32 %0, %1, %2" : "=v"(r) : "v"(lo), "v"(hi));
  return r;
}

// ---------------------------------------------------------------- MFMA GEMV (K-split partials)
// 512 threads = 8 waves = 128 rows/block. x-slice staged in LDS (contiguous HBM
// bursts); W read with unroll-8 hoisted loads => 1KB bursts per row visit.
// MODE 0 additionally fuses RMSNorm-1: x = bf16(hidden * rsqrt(mean(h^2)+eps) * ln1),
// computed from read-only inputs (hidden, ln1) — no cross-block coherence hazard.
template <int MODE, int KS, int CHT>
__global__ __launch_bounds__(512, 4) void gemv_mfma_k(
    const float* __restrict__ W0, const float* __restrict__ W1,
    const float* __restrict__ W2, const unsigned short* __restrict__ xbf,
    const float* __restrict__ xf, const float* __restrict__ rmsw,
    float* __restrict__ part, int O, int H) {
  __shared__ unsigned short xs[NB][CHT + 8];
  __shared__ float rs_s[NB];
  int t = threadIdx.x, lane = t & 63, wave = t >> 6;
  int rb = blockIdx.x, kc = blockIdx.y;
  int orow = rb * 128 + wave * 16 + (lane & 15);

  const float* Wp;
  if (MODE == 0) {
    if (orow < 4096) Wp = W0 + (size_t)orow * H;
    else if (orow < 5120) Wp = W1 + (size_t)(orow - 4096) * H;
    else Wp = W2 + (size_t)(orow - 5120) * H;
  } else if (MODE == 2) {
    Wp = (orow < FFN) ? W0 + (size_t)orow * H : W1 + (size_t)(orow - FFN) * H;
  } else {
    Wp = W0 + (size_t)orow * H;
  }

  if (MODE == 0) {
    // per-block redundant rms scales (reads only the immutable input `hidden`)
    for (int bb = wave; bb < NB; bb += 8) {
      const float* xb = xf + (size_t)bb * HH;
      float ss = 0.f;
      for (int i = lane * 4; i < HH; i += 256) {
        f4v v = *(const f4v*)(xb + i);
        ss += dot4(v, v);
      }
#pragma unroll
      for (int m = 1; m < 64; m <<= 1) ss += __shfl_xor(ss, m);
      if (lane == 0) rs_s[bb] = rsqrtf(ss * (1.0f / HH) + 1e-5f);
    }
    __syncthreads();
    constexpr int CPR = CHT / 8;
    for (int c = t; c < NB * CPR; c += 512) {
      int b = c / CPR, off = (c % CPR) * 8;
      const float* src = xf + (size_t)b * HH + (size_t)kc * CHT + off;
      f4v x0 = *(const f4v*)src;
      f4v x1 = *(const f4v*)(src + 4);
      f4v l0 = *(const f4v*)(rmsw + (size_t)kc * CHT + off);
      f4v l1 = *(const f4v*)(rmsw + (size_t)kc * CHT + off + 4);
      float sc_ = rs_s[b];
      u16x8 pk;
#pragma unroll
      for (int j = 0; j < 4; ++j) {
        pk[j] = f2bf(x0[j] * sc_ * l0[j]);
        pk[4 + j] = f2bf(x1[j] * sc_ * l1[j]);
      }
      *(u16x8*)&xs[b][off] = pk;
    }
  } else {
    // stage x tile: [16][CHT] bf16, contiguous 16B chunks
    constexpr int CPR = CHT / 8;
    for (int c = t; c < NB * CPR; c += 512) {
      int b = c / CPR, off = (c % CPR) * 8;
      *(u16x8*)&xs[b][off] =
          *(const u16x8*)(xbf + (size_t)b * H + (size_t)kc * CHT + off);
    }
  }
  __syncthreads();

  const unsigned short* xrow = &xs[lane & 15][(lane >> 4) * 8];
  const float* wp = Wp + (size_t)kc * CHT + (lane >> 4) * 8;

  f32x4 acc = {0.f, 0.f, 0.f, 0.f};
  constexpr int steps = CHT / 32;
#pragma unroll 8
  for (int s = 0; s < steps; ++s) {
    f4v w0 = ntload4(wp);
    f4v w1 = ntload4(wp + 4);
    bf16x8 a = *(const bf16x8*)(xrow + s * 32);
    bf16x8 bb;
#pragma unroll
    for (int j = 0; j < 4; ++j) {
      bb[j] = (short)f2bf(w0[j]);
      bb[4 + j] = (short)f2bf(w1[j]);
    }
    acc = __builtin_amdgcn_mfma_f32_16x16x32_bf16(a, bb, acc, 0, 0, 0);
    wp += 32;
  }
  float* pb = part + ((size_t)kc * NB + (size_t)((lane >> 4) * 4)) * O + orow;
#pragma unroll
  for (int r = 0; r < 4; ++r) pb[(size_t)r * O] = acc[r];
}

// ---------------------------------------------------------------- reduces
// rmsnorm2 fused with Wo-partial reduce + residual (KS=8)
__global__ void rmsnorm2_k(const float* __restrict__ hid, const float* __restrict__ p1,
                           const float* __restrict__ w, float* __restrict__ h2,
                           unsigned short* __restrict__ xn2) {
  int b = blockIdx.x;
  int t = threadIdx.x, lane = t & 63, wave = t >> 6;
  f4v v[4];
  float ss = 0.f;
#pragma unroll
  for (int i = 0; i < 4; ++i) {
    int h = 4 * (t + 256 * i);
    f4v s = *(const f4v*)(hid + (size_t)b * HH + h);
#pragma unroll
    for (int ks = 0; ks < 8; ++ks)
      s += *(const f4v*)(p1 + ((size_t)(ks * NB + b)) * HH + h);
    v[i] = s;
    ss += dot4(s, s);
  }
#pragma unroll
  for (int m = 1; m < 64; m <<= 1) ss += __shfl_xor(ss, m);
  __shared__ float red[4];
  if (lane == 0) red[wave] = ss;
  __syncthreads();
  float tot = red[0] + red[1] + red[2] + red[3];
  float rs = rsqrtf(tot * (1.0f / HH) + 1e-5f);
#pragma unroll
  for (int i = 0; i < 4; ++i) {
    int h = 4 * (t + 256 * i);
    *(f4v*)(h2 + (size_t)b * HH + h) = v[i];
    f4v wv = *(const f4v*)(w + h);
    f4v o = v[i] * rs * wv;
    u16x4 p;
#pragma unroll
    for (int j = 0; j < 4; ++j) p[j] = f2bf(o[j]);
    *(u16x4*)(xn2 + (size_t)b * HH + h) = p;
  }
}

// GU partial reduce (KS=4) + silu fuse -> bf16
__global__ void red_gu_k(const float* __restrict__ p2, unsigned short* __restrict__ gu) {
  int idx = blockIdx.x * 256 + threadIdx.x;    // 172*256 threads
  int pi = idx % 2752, b = idx / 2752;
  int p = pi * 4;
  f4v g = {0.f, 0.f, 0.f, 0.f}, u = {0.f, 0.f, 0.f, 0.f};
#pragma unroll
  for (int kk = 0; kk < 4; ++kk) {
    const float* base = p2 + ((size_t)(kk * NB + b)) * 22016;
    g += *(const f4v*)(base + p);
    u += *(const f4v*)(base + FFN + p);
  }
  u16x4 pk;
#pragma unroll
  for (int j = 0; j < 4; ++j) pk[j] = f2bf(silu_f(g[j]) * u[j]);
  *(u16x4*)(gu + (size_t)b * FFN + p) = pk;
}

__global__ void red_out_k(const float* __restrict__ h2, const float* __restrict__ p3,
                          float* __restrict__ out) {
  int idx = blockIdx.x * 256 + threadIdx.x;    // 64*256 threads
  int o = (idx & 1023) * 4, b = idx >> 10;
  f4v s = *(const f4v*)(h2 + (size_t)b * HH + o);
#pragma unroll
  for (int ks = 0; ks < 8; ++ks)
    s += *(const f4v*)(p3 + ((size_t)(ks * NB + b)) * HH + o);
  *(f4v*)(out + (size_t)b * HH + o) = s;
}

// ---------------------------------------------------------------- attention: split-S partials (MFMA QK^T)
__global__ __launch_bounds__(256, 4) void attn_part_k(
    const float* __restrict__ pq, const float* __restrict__ kcache,
    const float* __restrict__ vcache, float* __restrict__ pm,
    float* __restrict__ pl, float* __restrict__ pacc) {
  int c = blockIdx.x, kv = blockIdx.y, b = blockIdx.z;
  int t = threadIdx.x, lane = t & 63, wave = t >> 6;
  int ds = lane & 15, ss = lane >> 4;
  __shared__ float qs[GRP * HD];       // q fp32 for this (b,kv)
  __shared__ float sc[GRP][SCH];       // scores -> probabilities
  __shared__ float accw[4][GRP][HD];

  // reduce q from QKV k-split partials (cross-kernel boundary => coherent)
  {
    int i0 = t * 2;
#pragma unroll
    for (int i = i0; i < i0 + 2; ++i) {
      int off = kv * (GRP * HD) + i;
      float s = 0.f;
#pragma unroll
      for (int kk = 0; kk < QKS; ++kk)
        s += pq[((size_t)kk * NB + b) * 6144 + off];
      qs[i] = s;
    }
  }
  __syncthreads();

  // B fragments: col=group=ds (zero for ds>=4), k=(ss)*8+j, chunk kk covers d=kk*32..
  bf16x8 bq[4];
#pragma unroll
  for (int kk = 0; kk < 4; ++kk) {
    u32x4v w;
#pragma unroll
    for (int jj = 0; jj < 4; ++jj) {
      float f0 = 0.f, f1 = 0.f;
      if (ds < GRP) {
        int d = kk * 32 + ss * 8 + jj * 2;
        f0 = qs[ds * HD + d];
        f1 = qs[ds * HD + d + 1];
      }
      w[jj] = cvtpk(f0, f1);
    }
    bq[kk] = __builtin_bit_cast(bf16x8, w);
  }

  const size_t kvoff = ((size_t)b * NKV + kv) * (size_t)SC * HD;
  const float* kb = kcache + kvoff;

  // pass 1: QK^T via MFMA — each wave owns a 16-position tile per step
  for (int st = 0; st < SCH / 64; ++st) {
    int prel = (st * 4 + wave) * 16;
    const float* kr = kb + (size_t)(c * SCH + prel + ds) * HD + ss * 8;
    f32x4 d4 = {0.f, 0.f, 0.f, 0.f};
#pragma unroll
    for (int kk = 0; kk < 4; ++kk) {
      f4v k0 = ntload4(kr + kk * 32);
      f4v k1 = ntload4(kr + kk * 32 + 4);
      u32x4v w;
      w[0] = cvtpk(k0[0], k0[1]);
      w[1] = cvtpk(k0[2], k0[3]);
      w[2] = cvtpk(k1[0], k1[1]);
      w[3] = cvtpk(k1[2], k1[3]);
      d4 = __builtin_amdgcn_mfma_f32_16x16x32_bf16(
          __builtin_bit_cast(bf16x8, w), bq[kk], d4, 0, 0, 0);
    }
    if (ds < GRP) {
#pragma unroll
      for (int r = 0; r < 4; ++r) sc[ds][prel + ss * 4 + r] = d4[r] * SCALE;
    }
  }
  __syncthreads();

  // max + exp + sum per group (wave g owns group g); sc becomes probabilities
  size_t pbase = (((size_t)(b * NKV + kv)) * 8 + c) * GRP;
  {
    int g = wave;
    float m = -1e30f;
    for (int i = lane; i < SCH; i += 64) m = fmaxf(m, sc[g][i]);
#pragma unroll
    for (int mm = 1; mm < 64; mm <<= 1) m = fmaxf(m, __shfl_xor(m, mm));
    float lsum = 0.f;
    for (int i = lane; i < SCH; i += 64) {
      float e = __expf(sc[g][i] - m);
      sc[g][i] = e;
      lsum += e;
    }
#pragma unroll
    for (int mm = 1; mm < 64; mm <<= 1) lsum += __shfl_xor(lsum, mm);
    if (lane == 0) { pm[pbase + g] = m; pl[pbase + g] = lsum; }
  }
  __syncthreads();

  // pass 2: PV (p read from LDS, V streamed)
  float acc[GRP][8];
#pragma unroll
  for (int g = 0; g < GRP; ++g)
#pragma unroll
    for (int j = 0; j < 8; ++j) acc[g][j] = 0.f;
  const float* vb = vcache + kvoff;
  for (int st = 0; st < SCH / 16; ++st) {
    int sl = st * 16 + wave * 4 + ss;
    const float* vr = vb + (size_t)(c * SCH + sl) * HD + 8 * ds;
    f4v v0 = ntload4(vr);
    f4v v1 = ntload4(vr + 4);
    float p[GRP];
#pragma unroll
    for (int g = 0; g < GRP; ++g) p[g] = sc[g][sl];
#pragma unroll
    for (int g = 0; g < GRP; ++g) {
#pragma unroll
      for (int j = 0; j < 4; ++j) {
        acc[g][j] += p[g] * v0[j];
        acc[g][4 + j] += p[g] * v1[j];
      }
    }
  }
#pragma unroll
  for (int m = 16; m < 64; m <<= 1)
#pragma unroll
    for (int g = 0; g < GRP; ++g)
#pragma unroll
      for (int j = 0; j < 8; ++j) acc[g][j] += __shfl_xor(acc[g][j], m);
  if (ss == 0) {
#pragma unroll
    for (int g = 0; g < GRP; ++g)
#pragma unroll
      for (int j = 0; j < 4; ++j) {
        accw[wave][g][8 * ds + j] = acc[g][j];
        accw[wave][g][8 * ds + 4 + j] = acc[g][4 + j];
      }
  }
  __syncthreads();

  for (int idx = t; idx < GRP * HD; idx += 256) {
    int g = idx >> 7, dd = idx & 127;
    float o = accw[0][g][dd] + accw[1][g][dd] + accw[2][g][dd] + accw[3][g][dd];
    pacc[(pbase + g) * HD + dd] = o;
  }
}

// ---------------------------------------------------------------- attention: reduce + new token (bf16 out)
__global__ void attn_red_k(const float* __restrict__ pq, const float* __restrict__ pm,
                           const float* __restrict__ pl, const float* __restrict__ pacc,
                           unsigned short* __restrict__ attnb) {
  int bi = blockIdx.x;                 // 128 = 16b * 8kv
  int b = bi >> 3, kv = bi & 7;
  int t = threadIdx.x, lane = t & 63, wave = t >> 6;
  __shared__ float sn[GRP];
  {
    int g = wave;
    int qoff = kv * (GRP * HD) + g * HD + 2 * lane;
    int koff = 4096 + kv * HD + 2 * lane;
    float qx = 0.f, qy = 0.f, kx = 0.f, ky = 0.f;
#pragma unroll
    for (int kk = 0; kk < QKS; ++kk) {
      const float* pp = pq + ((size_t)kk * NB + b) * 6144;
      qx += pp[qoff]; qy += pp[qoff + 1];
      kx += pp[koff]; ky += pp[koff + 1];
    }
    float d = qx * kx + qy * ky;
#pragma unroll
    for (int m = 1; m < 64; m <<= 1) d += __shfl_xor(d, m);
    if (lane == 0) sn[g] = d * SCALE;
  }
  __syncthreads();
  size_t base = ((size_t)(b * NKV + kv)) * 8;
  for (int idx = t; idx < GRP * HD; idx += 256) {
    int g = idx >> 7, dd = idx & 127;
    float snv = sn[g];
    float M = snv;
    float pmv[8];
#pragma unroll
    for (int cc = 0; cc < 8; ++cc) {
      pmv[cc] = pm[(base + cc) * GRP + g];
      M = fmaxf(M, pmv[cc]);
    }
    float vnv = 0.f;
#pragma unroll
    for (int kk = 0; kk < QKS; ++kk)
      vnv += pq[((size_t)kk * NB + b) * 6144 + 5120 + kv * HD + dd];
    float en = __expf(snv - M);
    float L = en;
    float o = en * vnv;
#pragma unroll
    for (int cc = 0; cc < 8; ++cc) {
      float f = __expf(pmv[cc] - M);
      L += f * pl[(base + cc) * GRP + g];
      o += f * pacc[((base + cc) * GRP + g) * HD + dd];
    }
    attnb[(size_t)b * HH + (size_t)(kv * GRP + g) * HD + dd] = f2bf(o / L);
  }
}

// ---------------------------------------------------------------- launch
extern "C" void kernel_launch(void* const* d_in, const int* in_sizes, int n_in,
                              void* d_out, int out_size, void* d_ws, size_t ws_size,
                              hipStream_t stream) {
  const float* hidden = (const float*)d_in[0];
  const float* kc = (const float*)d_in[1];
  const float* vc = (const float*)d_in[2];
  const float* Wq = (const float*)d_in[3];
  const float* Wk = (const float*)d_in[4];
  const float* Wv = (const float*)d_in[5];
  const float* Wo = (const float*)d_in[6];
  const float* Wg = (const float*)d_in[7];
  const float* Wu = (const float*)d_in[8];
  const float* Wd = (const float*)d_in[9];
  const float* ln1 = (const float*)d_in[10];
  const float* ln2 = (const float*)d_in[11];
  float* out = (float*)d_out;

  // Workspace (floats), no aliasing. Total ~4.0M floats = 16.1 MB.
  float* p = (float*)d_ws;
  unsigned short* attnbf = (unsigned short*)p; p += 32768;
  float* h2 = p;    p += 65536;
  unsigned short* xn2bf = (unsigned short*)p;  p += 32768;
  unsigned short* gubf = (unsigned short*)p;   p += 88064;   // 16x11008 bf16
  float* pm = p;    p += 4096;
  float* pl = p;    p += 4096;
  float* pacc = p;  p += 524288;
  float* pq = p;    p += 786432;    // 8 x 16 x 6144
  float* p1 = p;    p += 524288;    // 8 x 16 x 4096
  float* p2 = p;    p += 1409024;   // 4 x 16 x 22016
  float* p3 = p;    p += 524288;    // 8 x 16 x 4096

  gemv_mfma_k<0, QKS, 512><<<dim3(48, QKS), 512, 0, stream>>>(
      Wq, Wk, Wv, nullptr, hidden, ln1, pq, 6144, 4096);
  attn_part_k<<<dim3(8, 8, 16), 256, 0, stream>>>(pq, kc, vc, pm, pl, pacc);
  attn_red_k<<<128, 256, 0, stream>>>(pq, pm, pl, pacc, attnbf);
  gemv_mfma_k<1, 8, 512><<<dim3(32, 8), 512, 0, stream>>>(
      Wo, nullptr, nullptr, attnbf, nullptr, nullptr, p1, 4096, 4096);
  rmsnorm2_k<<<16, 256, 0, stream>>>(hidden, p1, ln2, h2, xn2bf);
  gemv_mfma_k<2, 4, 1024><<<dim3(172, 4), 512, 0, stream>>>(
      Wg, Wu, nullptr, xn2bf, nullptr, nullptr, p2, 22016, 4096);
  red_gu_k<<<172, 256, 0, stream>>>(p2, gubf);
  gemv_mfma_k<3, 8, 1376><<<dim3(32, 8), 512, 0, stream>>>(
      Wd, nullptr, nullptr, gubf, nullptr, nullptr, p3, 4096, 11008);
  red_out_k<<<64, 256, 0, stream>>>(h2, p3, out);
}

// Round 13
// 266.705 us; speedup vs baseline: 1.0839x; 1.0839x over previous
//
#include <hip/hip_runtime.h>
#include <math.h>

#define HH   4096
#define NKV  8
#define GRP  4
#define HD   128
#define FFN  11008
#define NB   16
#define SC   4096
#define SCALE 0.08838834764831845f   // 1/sqrt(128)
#define SCH  512                      // attention chunk
#define QKS  8                        // QKV k-split (q partial chunks)

typedef float f4v __attribute__((ext_vector_type(4)));
typedef float f32x4 __attribute__((ext_vector_type(4)));
typedef short bf16x8 __attribute__((ext_vector_type(8)));
typedef unsigned short u16x4 __attribute__((ext_vector_type(4)));
typedef unsigned short u16x8 __attribute__((ext_vector_type(8)));
typedef unsigned int u32x4v __attribute__((ext_vector_type(4)));

__device__ __forceinline__ f4v ntload4(const float* p) {
  return __builtin_nontemporal_load((const f4v*)p);
}
__device__ __forceinline__ float dot4(f4v a, f4v b) {
  return a[0] * b[0] + a[1] * b[1] + a[2] * b[2] + a[3] * b[3];
}
__device__ __forceinline__ unsigned short f2bf(float f) {
  unsigned int u = __builtin_bit_cast(unsigned int, f);
  u += 0x7fffu + ((u >> 16) & 1u);
  return (unsigned short)(u >> 16);
}
__device__ __forceinline__ float silu_f(float g) { return g / (1.f + __expf(-g)); }
// packed fp32->bf16 (RNE) — ATTENTION KERNELS ONLY (GEMV with this asm NaN'd in R8/R9)
__device__ __forceinline__ unsigned int cvtpk(float lo, float hi) {
  unsigned int r;
  asm("v_cvt_pk_bf16_f32 %0, %1, %2" : "=v"(r) : "v"(lo), "v"(hi));
  return r;
}

// ---------------------------------------------------------------- RMSNorm (fp32 in, bf16 out)
__global__ void rmsnorm_bf_k(const float* __restrict__ x, const float* __restrict__ w,
                             unsigned short* __restrict__ y) {
  int b = blockIdx.x;
  const float* xb = x + (size_t)b * HH;
  unsigned short* yb = y + (size_t)b * HH;
  int t = threadIdx.x, lane = t & 63, wave = t >> 6;
  f4v v[4];
  float ss = 0.f;
#pragma unroll
  for (int i = 0; i < 4; ++i) {
    v[i] = *(const f4v*)(xb + 4 * (t + 256 * i));
    ss += dot4(v[i], v[i]);
  }
#pragma unroll
  for (int m = 1; m < 64; m <<= 1) ss += __shfl_xor(ss, m);
  __shared__ float red[4];
  if (lane == 0) red[wave] = ss;
  __syncthreads();
  float tot = red[0] + red[1] + red[2] + red[3];
  float rs = rsqrtf(tot * (1.0f / HH) + 1e-5f);
#pragma unroll
  for (int i = 0; i < 4; ++i) {
    int h = 4 * (t + 256 * i);
    f4v wv = *(const f4v*)(w + h);
    f4v o = v[i] * rs * wv;
    u16x4 p;
#pragma unroll
    for (int j = 0; j < 4; ++j) p[j] = f2bf(o[j]);
    *(u16x4*)(yb + h) = p;
  }
}

// ---------------------------------------------------------------- MFMA GEMV (K-split partials)
// 256 threads = 4 waves = 64 rows/block (VGPR headroom for deep unroll).
// x-slice staged in LDS (contiguous HBM bursts); W read with unroll-8 hoisted
// loads => 1KB contiguous bursts per row visit, ~16 loads in flight per wave.
template <int MODE, int KS, int CHT>
__global__ __launch_bounds__(256, 4) void gemv_mfma_k(
    const float* __restrict__ W0, const float* __restrict__ W1,
    const float* __restrict__ W2, const unsigned short* __restrict__ xbf,
    float* __restrict__ part, int O, int H) {
  __shared__ unsigned short xs[NB][CHT + 8];
  int t = threadIdx.x, lane = t & 63, wave = t >> 6;
  int rb = blockIdx.x, kc = blockIdx.y;
  int orow = rb * 64 + wave * 16 + (lane & 15);

  const float* Wp;
  if (MODE == 0) {
    if (orow < 4096) Wp = W0 + (size_t)orow * H;
    else if (orow < 5120) Wp = W1 + (size_t)(orow - 4096) * H;
    else Wp = W2 + (size_t)(orow - 5120) * H;
  } else if (MODE == 2) {
    Wp = (orow < FFN) ? W0 + (size_t)orow * H : W1 + (size_t)(orow - FFN) * H;
  } else {
    Wp = W0 + (size_t)orow * H;
  }

  // stage x tile: [16][CHT] bf16, contiguous 16B chunks
  {
    constexpr int CPR = CHT / 8;             // 16B chunks per row
    for (int c = t; c < NB * CPR; c += 256) {
      int b = c / CPR, off = (c % CPR) * 8;
      *(u16x8*)&xs[b][off] =
          *(const u16x8*)(xbf + (size_t)b * H + (size_t)kc * CHT + off);
    }
  }
  __syncthreads();

  const unsigned short* xrow = &xs[lane & 15][(lane >> 4) * 8];
  const float* wp = Wp + (size_t)kc * CHT + (lane >> 4) * 8;

  f32x4 acc = {0.f, 0.f, 0.f, 0.f};
  constexpr int steps = CHT / 32;
#pragma unroll 8
  for (int s = 0; s < steps; ++s) {
    f4v w0 = ntload4(wp);
    f4v w1 = ntload4(wp + 4);
    bf16x8 a = *(const bf16x8*)(xrow + s * 32);
    bf16x8 bb;
#pragma unroll
    for (int j = 0; j < 4; ++j) {
      bb[j] = (short)f2bf(w0[j]);
      bb[4 + j] = (short)f2bf(w1[j]);
    }
    acc = __builtin_amdgcn_mfma_f32_16x16x32_bf16(a, bb, acc, 0, 0, 0);
    wp += 32;
  }
  float* pb = part + ((size_t)kc * NB + (size_t)((lane >> 4) * 4)) * O + orow;
#pragma unroll
  for (int r = 0; r < 4; ++r) pb[(size_t)r * O] = acc[r];
}

// ---------------------------------------------------------------- reduces
// rmsnorm2 fused with Wo-partial reduce + residual (KS=8)
__global__ void rmsnorm2_k(const float* __restrict__ hid, const float* __restrict__ p1,
                           const float* __restrict__ w, float* __restrict__ h2,
                           unsigned short* __restrict__ xn2) {
  int b = blockIdx.x;
  int t = threadIdx.x, lane = t & 63, wave = t >> 6;
  f4v v[4];
  float ss = 0.f;
#pragma unroll
  for (int i = 0; i < 4; ++i) {
    int h = 4 * (t + 256 * i);
    f4v s = *(const f4v*)(hid + (size_t)b * HH + h);
#pragma unroll
    for (int ks = 0; ks < 8; ++ks)
      s += *(const f4v*)(p1 + ((size_t)(ks * NB + b)) * HH + h);
    v[i] = s;
    ss += dot4(s, s);
  }
#pragma unroll
  for (int m = 1; m < 64; m <<= 1) ss += __shfl_xor(ss, m);
  __shared__ float red[4];
  if (lane == 0) red[wave] = ss;
  __syncthreads();
  float tot = red[0] + red[1] + red[2] + red[3];
  float rs = rsqrtf(tot * (1.0f / HH) + 1e-5f);
#pragma unroll
  for (int i = 0; i < 4; ++i) {
    int h = 4 * (t + 256 * i);
    *(f4v*)(h2 + (size_t)b * HH + h) = v[i];
    f4v wv = *(const f4v*)(w + h);
    f4v o = v[i] * rs * wv;
    u16x4 p;
#pragma unroll
    for (int j = 0; j < 4; ++j) p[j] = f2bf(o[j]);
    *(u16x4*)(xn2 + (size_t)b * HH + h) = p;
  }
}

// GU partial reduce (KS=4) + silu fuse -> bf16
__global__ void red_gu_k(const float* __restrict__ p2, unsigned short* __restrict__ gu) {
  int idx = blockIdx.x * 256 + threadIdx.x;    // 172*256 threads
  int pi = idx % 2752, b = idx / 2752;
  int p = pi * 4;
  f4v g = {0.f, 0.f, 0.f, 0.f}, u = {0.f, 0.f, 0.f, 0.f};
#pragma unroll
  for (int kk = 0; kk < 4; ++kk) {
    const float* base = p2 + ((size_t)(kk * NB + b)) * 22016;
    g += *(const f4v*)(base + p);
    u += *(const f4v*)(base + FFN + p);
  }
  u16x4 pk;
#pragma unroll
  for (int j = 0; j < 4; ++j) pk[j] = f2bf(silu_f(g[j]) * u[j]);
  *(u16x4*)(gu + (size_t)b * FFN + p) = pk;
}

__global__ void red_out_k(const float* __restrict__ h2, const float* __restrict__ p3,
                          float* __restrict__ out) {
  int idx = blockIdx.x * 256 + threadIdx.x;    // 64*256 threads
  int o = (idx & 1023) * 4, b = idx >> 10;
  f4v s = *(const f4v*)(h2 + (size_t)b * HH + o);
#pragma unroll
  for (int ks = 0; ks < 8; ++ks)
    s += *(const f4v*)(p3 + ((size_t)(ks * NB + b)) * HH + o);
  *(f4v*)(out + (size_t)b * HH + o) = s;
}

// ---------------------------------------------------------------- attention: split-S partials (MFMA QK^T)
__global__ __launch_bounds__(256, 4) void attn_part_k(
    const float* __restrict__ pq, const float* __restrict__ kcache,
    const float* __restrict__ vcache, float* __restrict__ pm,
    float* __restrict__ pl, float* __restrict__ pacc) {
  int c = blockIdx.x, kv = blockIdx.y, b = blockIdx.z;
  int t = threadIdx.x, lane = t & 63, wave = t >> 6;
  int ds = lane & 15, ss = lane >> 4;
  __shared__ float qs[GRP * HD];       // q fp32 for this (b,kv)
  __shared__ float sc[GRP][SCH];       // scores -> probabilities
  __shared__ float accw[4][GRP][HD];

  // reduce q from QKV k-split partials (cross-kernel boundary => coherent)
  {
    int i0 = t * 2;
#pragma unroll
    for (int i = i0; i < i0 + 2; ++i) {
      int off = kv * (GRP * HD) + i;
      float s = 0.f;
#pragma unroll
      for (int kk = 0; kk < QKS; ++kk)
        s += pq[((size_t)kk * NB + b) * 6144 + off];
      qs[i] = s;
    }
  }
  __syncthreads();

  // B fragments: col=group=ds (zero for ds>=4), k=(ss)*8+j, chunk kk covers d=kk*32..
  bf16x8 bq[4];
#pragma unroll
  for (int kk = 0; kk < 4; ++kk) {
    u32x4v w;
#pragma unroll
    for (int jj = 0; jj < 4; ++jj) {
      float f0 = 0.f, f1 = 0.f;
      if (ds < GRP) {
        int d = kk * 32 + ss * 8 + jj * 2;
        f0 = qs[ds * HD + d];
        f1 = qs[ds * HD + d + 1];
      }
      w[jj] = cvtpk(f0, f1);
    }
    bq[kk] = __builtin_bit_cast(bf16x8, w);
  }

  const size_t kvoff = ((size_t)b * NKV + kv) * (size_t)SC * HD;
  const float* kb = kcache + kvoff;

  // pass 1: QK^T via MFMA — each wave owns a 16-position tile per step
  for (int st = 0; st < SCH / 64; ++st) {
    int prel = (st * 4 + wave) * 16;
    const float* kr = kb + (size_t)(c * SCH + prel + ds) * HD + ss * 8;
    f32x4 d4 = {0.f, 0.f, 0.f, 0.f};
#pragma unroll
    for (int kk = 0; kk < 4; ++kk) {
      f4v k0 = *(const f4v*)(kr + kk * 32);
      f4v k1 = *(const f4v*)(kr + kk * 32 + 4);
      u32x4v w;
      w[0] = cvtpk(k0[0], k0[1]);
      w[1] = cvtpk(k0[2], k0[3]);
      w[2] = cvtpk(k1[0], k1[1]);
      w[3] = cvtpk(k1[2], k1[3]);
      d4 = __builtin_amdgcn_mfma_f32_16x16x32_bf16(
          __builtin_bit_cast(bf16x8, w), bq[kk], d4, 0, 0, 0);
    }
    if (ds < GRP) {
#pragma unroll
      for (int r = 0; r < 4; ++r) sc[ds][prel + ss * 4 + r] = d4[r] * SCALE;
    }
  }
  __syncthreads();

  // max + exp + sum per group (wave g owns group g); sc becomes probabilities
  size_t pbase = (((size_t)(b * NKV + kv)) * 8 + c) * GRP;
  {
    int g = wave;
    float m = -1e30f;
    for (int i = lane; i < SCH; i += 64) m = fmaxf(m, sc[g][i]);
#pragma unroll
    for (int mm = 1; mm < 64; mm <<= 1) m = fmaxf(m, __shfl_xor(m, mm));
    float lsum = 0.f;
    for (int i = lane; i < SCH; i += 64) {
      float e = __expf(sc[g][i] - m);
      sc[g][i] = e;
      lsum += e;
    }
#pragma unroll
    for (int mm = 1; mm < 64; mm <<= 1) lsum += __shfl_xor(lsum, mm);
    if (lane == 0) { pm[pbase + g] = m; pl[pbase + g] = lsum; }
  }
  __syncthreads();

  // pass 2: PV (p read from LDS, V streamed)
  float acc[GRP][8];
#pragma unroll
  for (int g = 0; g < GRP; ++g)
#pragma unroll
    for (int j = 0; j < 8; ++j) acc[g][j] = 0.f;
  const float* vb = vcache + kvoff;
  for (int st = 0; st < SCH / 16; ++st) {
    int sl = st * 16 + wave * 4 + ss;
    const float* vr = vb + (size_t)(c * SCH + sl) * HD + 8 * ds;
    f4v v0 = ntload4(vr);
    f4v v1 = ntload4(vr + 4);
    float p[GRP];
#pragma unroll
    for (int g = 0; g < GRP; ++g) p[g] = sc[g][sl];
#pragma unroll
    for (int g = 0; g < GRP; ++g) {
#pragma unroll
      for (int j = 0; j < 4; ++j) {
        acc[g][j] += p[g] * v0[j];
        acc[g][4 + j] += p[g] * v1[j];
      }
    }
  }
#pragma unroll
  for (int m = 16; m < 64; m <<= 1)
#pragma unroll
    for (int g = 0; g < GRP; ++g)
#pragma unroll
      for (int j = 0; j < 8; ++j) acc[g][j] += __shfl_xor(acc[g][j], m);
  if (ss == 0) {
#pragma unroll
    for (int g = 0; g < GRP; ++g)
#pragma unroll
      for (int j = 0; j < 4; ++j) {
        accw[wave][g][8 * ds + j] = acc[g][j];
        accw[wave][g][8 * ds + 4 + j] = acc[g][4 + j];
      }
  }
  __syncthreads();

  for (int idx = t; idx < GRP * HD; idx += 256) {
    int g = idx >> 7, dd = idx & 127;
    float o = accw[0][g][dd] + accw[1][g][dd] + accw[2][g][dd] + accw[3][g][dd];
    pacc[(pbase + g) * HD + dd] = o;
  }
}

// ---------------------------------------------------------------- attention: reduce + new token (bf16 out)
__global__ void attn_red_k(const float* __restrict__ pq, const float* __restrict__ pm,
                           const float* __restrict__ pl, const float* __restrict__ pacc,
                           unsigned short* __restrict__ attnb) {
  int bi = blockIdx.x;                 // 128 = 16b * 8kv
  int b = bi >> 3, kv = bi & 7;
  int t = threadIdx.x, lane = t & 63, wave = t >> 6;
  __shared__ float sn[GRP];
  {
    int g = wave;
    int qoff = kv * (GRP * HD) + g * HD + 2 * lane;
    int koff = 4096 + kv * HD + 2 * lane;
    float qx = 0.f, qy = 0.f, kx = 0.f, ky = 0.f;
#pragma unroll
    for (int kk = 0; kk < QKS; ++kk) {
      const float* pp = pq + ((size_t)kk * NB + b) * 6144;
      qx += pp[qoff]; qy += pp[qoff + 1];
      kx += pp[koff]; ky += pp[koff + 1];
    }
    float d = qx * kx + qy * ky;
#pragma unroll
    for (int m = 1; m < 64; m <<= 1) d += __shfl_xor(d, m);
    if (lane == 0) sn[g] = d * SCALE;
  }
  __syncthreads();
  size_t base = ((size_t)(b * NKV + kv)) * 8;
  for (int idx = t; idx < GRP * HD; idx += 256) {
    int g = idx >> 7, dd = idx & 127;
    float snv = sn[g];
    float M = snv;
    float pmv[8];
#pragma unroll
    for (int cc = 0; cc < 8; ++cc) {
      pmv[cc] = pm[(base + cc) * GRP + g];
      M = fmaxf(M, pmv[cc]);
    }
    float vnv = 0.f;
#pragma unroll
    for (int kk = 0; kk < QKS; ++kk)
      vnv += pq[((size_t)kk * NB + b) * 6144 + 5120 + kv * HD + dd];
    float en = __expf(snv - M);
    float L = en;
    float o = en * vnv;
#pragma unroll
    for (int cc = 0; cc < 8; ++cc) {
      float f = __expf(pmv[cc] - M);
      L += f * pl[(base + cc) * GRP + g];
      o += f * pacc[((base + cc) * GRP + g) * HD + dd];
    }
    attnb[(size_t)b * HH + (size_t)(kv * GRP + g) * HD + dd] = f2bf(o / L);
  }
}

// ---------------------------------------------------------------- launch
extern "C" void kernel_launch(void* const* d_in, const int* in_sizes, int n_in,
                              void* d_out, int out_size, void* d_ws, size_t ws_size,
                              hipStream_t stream) {
  const float* hidden = (const float*)d_in[0];
  const float* kc = (const float*)d_in[1];
  const float* vc = (const float*)d_in[2];
  const float* Wq = (const float*)d_in[3];
  const float* Wk = (const float*)d_in[4];
  const float* Wv = (const float*)d_in[5];
  const float* Wo = (const float*)d_in[6];
  const float* Wg = (const float*)d_in[7];
  const float* Wu = (const float*)d_in[8];
  const float* Wd = (const float*)d_in[9];
  const float* ln1 = (const float*)d_in[10];
  const float* ln2 = (const float*)d_in[11];
  float* out = (float*)d_out;

  // Workspace (floats), no aliasing. Total ~4.05M floats = 16.2 MB.
  float* p = (float*)d_ws;
  unsigned short* xn1bf = (unsigned short*)p;  p += 32768;   // 16x4096 bf16
  unsigned short* attnbf = (unsigned short*)p; p += 32768;
  float* h2 = p;    p += 65536;
  unsigned short* xn2bf = (unsigned short*)p;  p += 32768;
  unsigned short* gubf = (unsigned short*)p;   p += 88064;   // 16x11008 bf16
  float* pm = p;    p += 4096;
  float* pl = p;    p += 4096;
  float* pacc = p;  p += 524288;
  float* pq = p;    p += 786432;    // 8 x 16 x 6144
  float* p1 = p;    p += 524288;    // 8 x 16 x 4096
  float* p2 = p;    p += 1409024;   // 4 x 16 x 22016
  float* p3 = p;    p += 524288;    // 8 x 16 x 4096

  rmsnorm_bf_k<<<16, 256, 0, stream>>>(hidden, ln1, xn1bf);
  gemv_mfma_k<0, QKS, 512><<<dim3(96, QKS), 256, 0, stream>>>(Wq, Wk, Wv, xn1bf, pq, 6144, 4096);
  attn_part_k<<<dim3(8, 8, 16), 256, 0, stream>>>(pq, kc, vc, pm, pl, pacc);
  attn_red_k<<<128, 256, 0, stream>>>(pq, pm, pl, pacc, attnbf);
  gemv_mfma_k<1, 8, 512><<<dim3(64, 8), 256, 0, stream>>>(Wo, nullptr, nullptr, attnbf, p1, 4096, 4096);
  rmsnorm2_k<<<16, 256, 0, stream>>>(hidden, p1, ln2, h2, xn2bf);
  gemv_mfma_k<2, 4, 1024><<<dim3(344, 4), 256, 0, stream>>>(Wg, Wu, nullptr, xn2bf, p2, 22016, 4096);
  red_gu_k<<<172, 256, 0, stream>>>(p2, gubf);
  gemv_mfma_k<3, 8, 1376><<<dim3(64, 8), 256, 0, stream>>>(Wd, nullptr, nullptr, gubf, p3, 4096, 11008);
  red_out_k<<<64, 256, 0, stream>>>(h2, p3, out);
}